// Round 2
// baseline (333.746 us; speedup 1.0000x reference)
//
#include <hip/hip_runtime.h>
#include <math.h>

// VectorQuantizer: inputs [64,32,32,64] f32, codebook [64,512] f32.
// Outputs (flat f32): ste[4194304], perplexity, codebook_loss, commitment_loss.
//
// ws layout (floats): Cn[512] | cbT[512*64] | counts[512] (as uint) | lossSum[1]

#define NUM_K   512
#define DIM     64
#define NROWS   65536
#define KT      128      // k-tile width staged in LDS (32 KB — under the 64 KB static limit)
#define NJ      (KT/64)  // columns per lane per k-tile = 2
#define TR      8        // rows per thread (register blocking)
#define ROWTILE 64       // rows per block tile (8 waves * 8 rows)
#define NTILES  (NROWS / ROWTILE)
#define NELEM   (NROWS * DIM)

__global__ __launch_bounds__(512) void vq_prep(const float* __restrict__ cb,
                                               float* __restrict__ Cn,
                                               float* __restrict__ cbT,
                                               unsigned int* __restrict__ counts,
                                               float* __restrict__ lossSum)
{
    int k = threadIdx.x;  // 0..511
    float a = 0.0f;
    #pragma unroll
    for (int d = 0; d < DIM; ++d) {
        float v = cb[d * NUM_K + k];        // coalesced across k
        a = fmaf(v, v, a);
        cbT[k * DIM + d] = v;               // transposed copy for row gathers
    }
    Cn[k] = a;                              // ||e_k||^2, sequential-d order
    counts[k] = 0u;
    if (k == 0) *lossSum = 0.0f;
}

__global__ __launch_bounds__(512) void vq_main(const float* __restrict__ x,
                                               const float* __restrict__ cb,
                                               const float* __restrict__ Cn,
                                               const float* __restrict__ cbT,
                                               unsigned int* __restrict__ counts,
                                               float* __restrict__ lossSum,
                                               float* __restrict__ out)
{
    __shared__ float ecb[DIM * KT];   // 32 KB codebook k-tile, [d][k] row-major
    __shared__ float lossAcc;
    const int tid = threadIdx.x;
    if (tid == 0) lossAcc = 0.0f;
    const int tc = tid & 63;                                   // lane
    const int tr = __builtin_amdgcn_readfirstlane(tid >> 6);   // wave id, forced uniform

    for (int tile = blockIdx.x; tile < NTILES; tile += gridDim.x) {
        const int rowBase = tile * ROWTILE + tr * TR;  // this wave's 8 rows
        const float* xr[TR];
        #pragma unroll
        for (int i = 0; i < TR; ++i) xr[i] = x + (size_t)(rowBase + i) * DIM;

        // ||x||^2 per row (butterfly sum; every lane ends with the value)
        float Ar[TR];
        #pragma unroll
        for (int i = 0; i < TR; ++i) {
            float v = xr[i][tc];
            float p = v * v;
            #pragma unroll
            for (int s = 1; s < 64; s <<= 1) p += __shfl_xor(p, s, 64);
            Ar[i] = p;
        }

        float bestD[TR]; int bestK[TR];
        #pragma unroll
        for (int i = 0; i < TR; ++i) { bestD[i] = 3.4e38f; bestK[i] = 0; }

        for (int kt = 0; kt < NUM_K; kt += KT) {
            __syncthreads();   // previous tile fully consumed
            {   // stage codebook tile [DIM][KT]: 512 threads * 4 float4 = 8192 floats
                const int dd = tid >> 3;        // 0..63 = d row (8 threads per row)
                const int m  = tid & 7;
                const float* src = cb + dd * NUM_K + kt;
                float* dst = ecb + dd * KT;
                #pragma unroll
                for (int s = 0; s < 4; ++s) {
                    int o = 4 * (m + 8 * s);
                    *(float4*)(dst + o) = *(const float4*)(src + o);
                }
            }
            __syncthreads();

            float acc[TR][NJ];
            #pragma unroll
            for (int i = 0; i < TR; ++i)
                #pragma unroll
                for (int j = 0; j < NJ; ++j) acc[i][j] = 0.0f;

            // s[i][j] = x_row(i) . e_col(kt + NJ*tc + j)
            #pragma unroll
            for (int d = 0; d < DIM; d += 4) {
                float4 xv[TR];
                #pragma unroll
                for (int i = 0; i < TR; ++i)
                    xv[i] = *(const float4*)(xr[i] + d);   // wave-uniform -> scalar loads
                #pragma unroll
                for (int d2 = 0; d2 < 4; ++d2) {
                    float2 ev = *(const float2*)(ecb + (d + d2) * KT + NJ * tc);
                    #pragma unroll
                    for (int i = 0; i < TR; ++i) {
                        float xs = (d2 == 0) ? xv[i].x : (d2 == 1) ? xv[i].y
                                 : (d2 == 2) ? xv[i].z : xv[i].w;
                        acc[i][0] = fmaf(xs, ev.x, acc[i][0]);
                        acc[i][1] = fmaf(xs, ev.y, acc[i][1]);
                    }
                }
            }

            // distances in the reference's op order: (||x||^2 - 2s) + ||e||^2
            const float2 Cv = *(const float2*)(Cn + kt + NJ * tc);
            #pragma unroll
            for (int i = 0; i < TR; ++i) {
                #pragma unroll
                for (int j = 0; j < NJ; ++j) {
                    float cj = (j == 0) ? Cv.x : Cv.y;
                    float dist = (Ar[i] - 2.0f * acc[i][j]) + cj;
                    int kk = kt + NJ * tc + j;
                    if (dist < bestD[i]) { bestD[i] = dist; bestK[i] = kk; }
                }
            }
        }

        // wave-wide lexicographic argmin per row (ties -> lowest k, like jnp.argmin)
        #pragma unroll
        for (int i = 0; i < TR; ++i) {
            float bd = bestD[i]; int bk = bestK[i];
            #pragma unroll
            for (int s = 1; s < 64; s <<= 1) {
                float od = __shfl_xor(bd, s, 64);
                int   ok = __shfl_xor(bk, s, 64);
                if (od < bd || (od == bd && ok < bk)) { bd = od; bk = ok; }
            }
            bestD[i] = bd; bestK[i] = bk;
        }

        // ste rows: x + (q - x); 64 lanes per row, coalesced 256B
        #pragma unroll
        for (int i = 0; i < TR; ++i) {
            float q  = cbT[bestK[i] * DIM + tc];
            float xv = xr[i][tc];
            out[(size_t)(rowBase + i) * DIM + tc] = xv + (q - xv);
        }
        // histogram + loss (min distance IS the row's squared error)
        if (tc == 0) {
            float s8 = 0.0f;
            #pragma unroll
            for (int i = 0; i < TR; ++i) {
                atomicAdd(&counts[bestK[i]], 1u);
                s8 += bestD[i];
            }
            atomicAdd(&lossAcc, s8);
        }
    }
    __syncthreads();
    if (tid == 0) atomicAdd(lossSum, lossAcc);
}

__global__ __launch_bounds__(512) void vq_final(const unsigned int* __restrict__ counts,
                                                const float* __restrict__ lossSum,
                                                float* __restrict__ out)
{
    __shared__ float wsum[8];
    int t = threadIdx.x;  // 0..511
    float p = (float)counts[t] * (1.0f / 65536.0f);
    float term = p * logf(p + 1e-10f);
    #pragma unroll
    for (int s = 1; s < 64; s <<= 1) term += __shfl_xor(term, s, 64);
    if ((t & 63) == 0) wsum[t >> 6] = term;
    __syncthreads();
    if (t == 0) {
        float s = 0.0f;
        #pragma unroll
        for (int w = 0; w < 8; ++w) s += wsum[w];
        out[NELEM] = expf(-s);                       // perplexity
        float m = (*lossSum) * (1.0f / (float)NELEM);
        out[NELEM + 1] = m;                          // codebook loss
        out[NELEM + 2] = 0.25f * m;                  // commitment loss = BETA * m
    }
}

extern "C" void kernel_launch(void* const* d_in, const int* in_sizes, int n_in,
                              void* d_out, int out_size, void* d_ws, size_t ws_size,
                              hipStream_t stream)
{
    const float* x  = (const float*)d_in[0];   // [65536,64]
    const float* cb = (const float*)d_in[1];   // [64,512]
    float* out = (float*)d_out;

    float* wsf = (float*)d_ws;
    float* Cn  = wsf;                                   // 512
    float* cbT = wsf + NUM_K;                           // 512*64
    unsigned int* counts = (unsigned int*)(wsf + NUM_K + NUM_K * DIM);  // 512
    float* lossSum = (float*)(wsf + NUM_K + NUM_K * DIM + NUM_K);       // 1

    vq_prep <<<1,    512, 0, stream>>>(cb, Cn, cbT, counts, lossSum);
    vq_main <<<1024, 512, 0, stream>>>(x, cb, Cn, cbT, counts, lossSum, out);
    vq_final<<<1,    512, 0, stream>>>(counts, lossSum, out);
}